// Round 2
// baseline (87.216 us; speedup 1.0000x reference)
//
#include <hip/hip_runtime.h>

// Problem constants (from reference setup_inputs)
#define NN 8
#define CC 4
#define HH 64
#define WW 64
#define KK 5
#define FF 16
#define HO 60
#define WO 60
#define PP (KK * KK * CC) /* 100 */

typedef float v4f __attribute__((ext_vector_type(4)));
typedef float v2f __attribute__((ext_vector_type(2)));

// ws layout: wq[p*16 + side*8 + f2] = {e^ka, e^kb, ka*e^ka, kb*e^kb}
// where f2 indexes feature pairs (features 2*f2, 2*f2+1), side 0 = k1, 1 = k2.
__global__ void smorph_weights(const float* __restrict__ k1,
                               const float* __restrict__ k2,
                               float4* __restrict__ wq) {
    int i = blockIdx.x * blockDim.x + threadIdx.x;
    if (i < PP * FF) {
        int p = i >> 4, rem = i & 15, side = rem >> 3, f2 = rem & 7;
        const float* kp = side ? k2 : k1;
        float ka = kp[p * FF + 2 * f2];
        float kb = kp[p * FF + 2 * f2 + 1];
        float ea = __expf(ka), eb = __expf(kb);
        wq[i] = make_float4(ea, eb, ka * ea, kb * eb);
    }
}

// Theory for this version: round-1 kernel was LDS-pipe bound (~2050 b128 LDS
// ops/block, 4/5 of them broadcast weight reads) at 3.75 waves/SIMD.
// Fixes: (1) weights via wave-uniform global_load_dwordx4 (vmcnt pipe,
// independent of ds_read's lgkmcnt -> compiler can pipeline; NO readfirstlane
// so the load cannot be scalarized into the lgkm-mixing s_load), (2) 16-wave
// blocks (4 fg x 4 c) -> 7.5 waves/SIMD, (3) pixel quads batched 5-at-a-time
// into registers per (c,kh) phase.
//
// Block = one (n, ho): 1024 threads = 16 waves.
//   wave wid: fg = wid&3 (features 4fg..4fg+3 as f-pairs 2fg, 2fg+1)
//             cw = wid>>2 (c slice, one channel per wave)
//   lane = w position (60 used of 64).
__global__ __launch_bounds__(1024) void smorph_conv(
        const float* __restrict__ x, const v4f* __restrict__ wq,
        const float* __restrict__ bias, float* __restrict__ out) {
    __shared__ v4f pq[CC * KK * 64 + 4];  // +4 pad: lanes 60-63 read wo+kw<=67
    __shared__ v2f red[3][4][8][64];      // c-partials: [cw-1][fg][acc][lane]

    int b = blockIdx.x; // 0..479 = (n, ho)
    int n = b / HO;
    int ho = b - n * HO;
    int t = threadIdx.x;

    // Stage pixel exp-quads: rows ho..ho+4 (ho+4 <= 63 always), all c, w 0..63.
    for (int i = t; i < CC * KK * 64; i += 1024) {
        int w = i & 63;
        int cr = i >> 6; // c*KK + r
        int c = cr / KK, r = cr - c * KK;
        float v = x[((n * CC + c) * HH + (ho + r)) * WW + w];
        float e1 = __expf(v), e2 = __expf(-v);
        v4f qv = {e1, v * e1, e2, -v * e2};
        pq[i] = qv;
    }
    __syncthreads();

    int lane = t & 63; // w position
    int wid = t >> 6;  // 0..15
    int fg = wid & 3;  // feature group (NOT readfirstlane'd: keeps weight
    int cw = wid >> 2; // loads as vector global_load on the vmcnt pipe)

    v2f d1[2], n1[2], d2[2], n2[2];
#pragma unroll
    for (int jj = 0; jj < 2; ++jj) {
        d1[jj] = 0.f; n1[jj] = 0.f; d2[jj] = 0.f; n2[jj] = 0.f;
    }

#pragma unroll
    for (int kh = 0; kh < KK; ++kh) {
        // Phase: batch the 5 overlapping pixel quads for this (cw, kh) row
        // into registers (one lgkm group), then pure fma + weight vmcnt loads.
        const v4f* prow = &pq[(cw * KK + kh) * 64 + lane];
        v4f q[KK];
#pragma unroll
        for (int kw = 0; kw < KK; ++kw) q[kw] = prow[kw];
#pragma unroll
        for (int kw = 0; kw < KK; ++kw) {
            // p = (kh*KK + kw)*CC + cw  (reference patch order: kh,kw,c)
            const v4f* wp = wq + ((kh * KK + kw) * CC + cw) * 16 + fg * 2;
            v4f w1a = wp[0], w1b = wp[1];     // side 1, f-pairs 2fg, 2fg+1
            v4f w2a = wp[8], w2b = wp[9];     // side 2
            v4f qv = q[kw];
            d1[0] += qv.xx * w1a.xy;
            n1[0] += qv.yy * w1a.xy + qv.xx * w1a.zw;
            d1[1] += qv.xx * w1b.xy;
            n1[1] += qv.yy * w1b.xy + qv.xx * w1b.zw;
            d2[0] += qv.zz * w2a.xy;
            n2[0] += qv.ww * w2a.xy + qv.zz * w2a.zw;
            d2[1] += qv.zz * w2b.xy;
            n2[1] += qv.ww * w2b.xy + qv.zz * w2b.zw;
        }
    }

    // c reduction: cw 1..3 dump partials, cw 0 combines and writes out.
    if (cw) {
        v2f* rr = &red[cw - 1][fg][0][lane];
        rr[0 * 64] = d1[0]; rr[1 * 64] = d1[1];
        rr[2 * 64] = n1[0]; rr[3 * 64] = n1[1];
        rr[4 * 64] = d2[0]; rr[5 * 64] = d2[1];
        rr[6 * 64] = n2[0]; rr[7 * 64] = n2[1];
    }
    __syncthreads();
    if (!cw && lane < WO) {
#pragma unroll
        for (int r = 0; r < 3; ++r) {
            const v2f* rr = &red[r][fg][0][lane];
            d1[0] += rr[0 * 64]; d1[1] += rr[1 * 64];
            n1[0] += rr[2 * 64]; n1[1] += rr[3 * 64];
            d2[0] += rr[4 * 64]; d2[1] += rr[5 * 64];
            n2[0] += rr[6 * 64]; n2[1] += rr[7 * 64];
        }
#pragma unroll
        for (int jp = 0; jp < 2; ++jp) {
            v2f o = n1[jp] / d1[jp] + n2[jp] / d2[jp];
            int f0 = fg * 4 + 2 * jp;
            out[((size_t)(n * FF + f0) * HO + ho) * WO + lane] = o.x + bias[f0];
            out[((size_t)(n * FF + f0 + 1) * HO + ho) * WO + lane] =
                o.y + bias[f0 + 1];
        }
    }
}

extern "C" void kernel_launch(void* const* d_in, const int* in_sizes, int n_in,
                              void* d_out, int out_size, void* d_ws, size_t ws_size,
                              hipStream_t stream) {
    const float* x    = (const float*)d_in[0];
    const float* k1   = (const float*)d_in[1];
    const float* k2   = (const float*)d_in[2];
    const float* bias = (const float*)d_in[3];
    float* out = (float*)d_out;

    float4* wqf = (float4*)d_ws;

    smorph_weights<<<(PP * FF + 255) / 256, 256, 0, stream>>>(k1, k2, wqf);
    // 8 n * 60 ho = 480 blocks, 1024 threads (16 waves: 4 fg x 4 c-slices)
    smorph_conv<<<480, 1024, 0, stream>>>(x, (const v4f*)d_ws, bias, out);
}